// Round 3
// baseline (250.657 us; speedup 1.0000x reference)
//
#include <hip/hip_runtime.h>
#include <math.h>

#define INFEAT 4096
#define CAPACITY 65536
#define EPS 1e-8f
#define NBLOCKS 2048           // x4 waves = 8192 waves; 8 contiguous rows/wave
#define ROWS_PER_WAVE 8

typedef float f32x4 __attribute__((ext_vector_type(4)));

__global__ __launch_bounds__(256, 8) void cosine_kernel(const float* __restrict__ x,
                                                        const float* __restrict__ memory,
                                                        float* __restrict__ out) {
    __shared__ float sx[INFEAT];        // 16 KB: x staged once per block
    __shared__ float partial[4];

    const int tid  = threadIdx.x;
    const int lane = tid & 63;
    const int wid  = tid >> 6;

    // ---- stage x into LDS + fused x_norm (reuses the mandatory barrier) ----
    const f32x4* x4  = reinterpret_cast<const f32x4*>(x);
    f32x4*       sx4 = reinterpret_cast<f32x4*>(sx);
    float ssx = 0.f;
    #pragma unroll
    for (int k = 0; k < 4; ++k) {
        f32x4 v = x4[tid + k * 256];
        sx4[tid + k * 256] = v;
        ssx = fmaf(v.x, v.x, ssx);
        ssx = fmaf(v.y, v.y, ssx);
        ssx = fmaf(v.z, v.z, ssx);
        ssx = fmaf(v.w, v.w, ssx);
    }
    #pragma unroll
    for (int off = 32; off > 0; off >>= 1) ssx += __shfl_down(ssx, off);
    if (lane == 0) partial[wid] = ssx;
    __syncthreads();
    const float xn = sqrtf(partial[0] + partial[1] + partial[2] + partial[3]);

    // ---- 8 contiguous rows per wave: linear 128 KB stream ----
    const int  wave = blockIdx.x * 4 + wid;
    const long row0 = (long)wave * ROWS_PER_WAVE;

    for (int r = 0; r < ROWS_PER_WAVE; ++r) {
        const long row = row0 + r;
        const f32x4* m4 =
            reinterpret_cast<const f32x4*>(memory + row * INFEAT);
        float dot0 = 0.f, dot1 = 0.f, ss0 = 0.f, ss1 = 0.f;  // 2-way ILP
        #pragma unroll
        for (int k = 0; k < 16; k += 2) {
            f32x4 a  = __builtin_nontemporal_load(&m4[lane + k * 64]);
            f32x4 b  = __builtin_nontemporal_load(&m4[lane + (k + 1) * 64]);
            f32x4 xa = sx4[lane + k * 64];          // ds_read_b128, conflict-free
            f32x4 xb = sx4[lane + (k + 1) * 64];
            dot0 = fmaf(a.x, xa.x, dot0);
            dot0 = fmaf(a.y, xa.y, dot0);
            dot0 = fmaf(a.z, xa.z, dot0);
            dot0 = fmaf(a.w, xa.w, dot0);
            ss0  = fmaf(a.x, a.x, ss0);
            ss0  = fmaf(a.y, a.y, ss0);
            ss0  = fmaf(a.z, a.z, ss0);
            ss0  = fmaf(a.w, a.w, ss0);
            dot1 = fmaf(b.x, xb.x, dot1);
            dot1 = fmaf(b.y, xb.y, dot1);
            dot1 = fmaf(b.z, xb.z, dot1);
            dot1 = fmaf(b.w, xb.w, dot1);
            ss1  = fmaf(b.x, b.x, ss1);
            ss1  = fmaf(b.y, b.y, ss1);
            ss1  = fmaf(b.z, b.z, ss1);
            ss1  = fmaf(b.w, b.w, ss1);
        }
        float dot = dot0 + dot1;
        float ss  = ss0 + ss1;
        #pragma unroll
        for (int off = 32; off > 0; off >>= 1) {
            dot += __shfl_down(dot, off);
            ss  += __shfl_down(ss, off);
        }
        if (lane == 0) {
            float denom = fmaxf(sqrtf(ss) * xn, EPS);
            __builtin_nontemporal_store(dot / denom, &out[row]);
        }
    }
}

extern "C" void kernel_launch(void* const* d_in, const int* in_sizes, int n_in,
                              void* d_out, int out_size, void* d_ws, size_t ws_size,
                              hipStream_t stream) {
    const float* x      = (const float*)d_in[0];   // [4096]
    const float* memory = (const float*)d_in[1];   // [65536, 4096]
    float* out = (float*)d_out;                    // [65536]

    cosine_kernel<<<NBLOCKS, 256, 0, stream>>>(x, memory, out);
}

// Round 4
// 221.123 us; speedup vs baseline: 1.1336x; 1.1336x over previous
//
#include <hip/hip_runtime.h>
#include <math.h>

#define INFEAT 4096
#define CAPACITY 65536
#define EPS 1e-8f
#define NWAVES 8192            // 2048 blocks x 4 waves; 8 rows/wave, stride-8192
#define RESIDENT_ROWS 14336    // prefix with normal (LLC-allocating) loads

typedef float f32x4 __attribute__((ext_vector_type(4)));

#define BODY(a, b, xa, xb)                                                     \
    dot0 = fmaf((a).x, (xa).x, dot0);                                          \
    dot0 = fmaf((a).y, (xa).y, dot0);                                          \
    dot0 = fmaf((a).z, (xa).z, dot0);                                          \
    dot0 = fmaf((a).w, (xa).w, dot0);                                          \
    ss0  = fmaf((a).x, (a).x, ss0);                                            \
    ss0  = fmaf((a).y, (a).y, ss0);                                            \
    ss0  = fmaf((a).z, (a).z, ss0);                                            \
    ss0  = fmaf((a).w, (a).w, ss0);                                            \
    dot1 = fmaf((b).x, (xb).x, dot1);                                          \
    dot1 = fmaf((b).y, (xb).y, dot1);                                          \
    dot1 = fmaf((b).z, (xb).z, dot1);                                          \
    dot1 = fmaf((b).w, (xb).w, dot1);                                          \
    ss1  = fmaf((b).x, (b).x, ss1);                                            \
    ss1  = fmaf((b).y, (b).y, ss1);                                            \
    ss1  = fmaf((b).z, (b).z, ss1);                                            \
    ss1  = fmaf((b).w, (b).w, ss1);

__global__ __launch_bounds__(256, 8) void cosine_kernel(const float* __restrict__ x,
                                                        const float* __restrict__ memory,
                                                        float* __restrict__ out) {
    __shared__ float sx[INFEAT];        // 16 KB: x staged once per block
    __shared__ float partial[4];

    const int tid  = threadIdx.x;
    const int lane = tid & 63;
    const int wid  = tid >> 6;

    // ---- stage x into LDS + fused x_norm (reuses the mandatory barrier) ----
    const f32x4* x4  = reinterpret_cast<const f32x4*>(x);
    f32x4*       sx4 = reinterpret_cast<f32x4*>(sx);
    float ssx = 0.f;
    #pragma unroll
    for (int k = 0; k < 4; ++k) {
        f32x4 v = x4[tid + k * 256];
        sx4[tid + k * 256] = v;
        ssx = fmaf(v.x, v.x, ssx);
        ssx = fmaf(v.y, v.y, ssx);
        ssx = fmaf(v.z, v.z, ssx);
        ssx = fmaf(v.w, v.w, ssx);
    }
    #pragma unroll
    for (int off = 32; off > 0; off >>= 1) ssx += __shfl_down(ssx, off);
    if (lane == 0) partial[wid] = ssx;
    __syncthreads();
    const float xn = sqrtf(partial[0] + partial[1] + partial[2] + partial[3]);

    // ---- R1's strided row mapping: all waves sweep a moving 128 MB window --
    const int wave = blockIdx.x * 4 + wid;

    for (int row = wave; row < CAPACITY; row += NWAVES) {
        const f32x4* m4 =
            reinterpret_cast<const f32x4*>(memory + (size_t)row * INFEAT);
        float dot0 = 0.f, dot1 = 0.f, ss0 = 0.f, ss1 = 0.f;

        if (row < RESIDENT_ROWS) {          // wave-uniform branch
            #pragma unroll
            for (int k = 0; k < 16; k += 2) {
                f32x4 a  = m4[lane + k * 64];
                f32x4 b  = m4[lane + (k + 1) * 64];
                f32x4 xa = sx4[lane + k * 64];        // ds_read_b128
                f32x4 xb = sx4[lane + (k + 1) * 64];
                BODY(a, b, xa, xb)
            }
        } else {
            #pragma unroll
            for (int k = 0; k < 16; k += 2) {
                f32x4 a  = __builtin_nontemporal_load(&m4[lane + k * 64]);
                f32x4 b  = __builtin_nontemporal_load(&m4[lane + (k + 1) * 64]);
                f32x4 xa = sx4[lane + k * 64];
                f32x4 xb = sx4[lane + (k + 1) * 64];
                BODY(a, b, xa, xb)
            }
        }

        float dot = dot0 + dot1;
        float ss  = ss0 + ss1;
        #pragma unroll
        for (int off = 32; off > 0; off >>= 1) {
            dot += __shfl_down(dot, off);
            ss  += __shfl_down(ss, off);
        }
        if (lane == 0) {
            float denom = fmaxf(sqrtf(ss) * xn, EPS);
            __builtin_nontemporal_store(dot / denom, &out[row]);
        }
    }
}

extern "C" void kernel_launch(void* const* d_in, const int* in_sizes, int n_in,
                              void* d_out, int out_size, void* d_ws, size_t ws_size,
                              hipStream_t stream) {
    const float* x      = (const float*)d_in[0];   // [4096]
    const float* memory = (const float*)d_in[1];   // [65536, 4096]
    float* out = (float*)d_out;                    // [65536]

    cosine_kernel<<<2048, 256, 0, stream>>>(x, memory, out);
}